// Round 6
// baseline (419.732 us; speedup 1.0000x reference)
//
#include <hip/hip_runtime.h>

#define KS 51
#define RAD 25
#define DIM 128
#define HW 64
#define XPS 84      // h2 per padded row (82 used) -> 336 B = 21*16B (odd, conflict-free)
#define XRN 114     // padded rows
#define WPS 52      // duplicated (w,w) h2 per ki row; slot 51 zeroed

typedef _Float16 h2 __attribute__((ext_vector_type(2)));

// coords = [0,1,2,4,8,16,25]; quantise = largest coord <= |o|; signed index 0..12
__device__ __forceinline__ int qidx(int o) {
  int a = o < 0 ? -o : o;
  int r;
  if (a >= 25)      r = 6;
  else if (a >= 16) r = 5;
  else if (a >= 8)  r = 4;
  else if (a >= 4)  r = 3;
  else if (a >= 2)  r = 2;
  else              r = a;
  return o < 0 ? 6 - r : 6 + r;
}

__launch_bounds__(256, 2)
__global__ void dwconv(const float* __restrict__ x, const float* __restrict__ comp,
                       const float* __restrict__ kpe, float* __restrict__ out) {
  __shared__ h2 xp[XRN * XPS];        // 38,304 B  pair tile: (px[i], px[i+32])
  __shared__ h2 w2[KS * WPS];         // 10,608 B  duplicated weights
  const int img = blockIdx.x;         // b*128 + c
  const int c   = img & (DIM - 1);
  const int tid = threadIdx.x;

  // ---- zero pair tile ----
  {
    uint4 z; z.x = z.y = z.z = z.w = 0u;
    uint4* p4 = (uint4*)xp;
    for (int i = tid; i < XRN * XPS / 4; i += 256) p4[i] = z;
  }
  // ---- build duplicated f16 weight table (disjoint from xp, no sync needed yet) ----
  const float* __restrict__ crow = comp + c * 169;
  for (int idx = tid; idx < KS * WPS; idx += 256) {
    const int ki = idx / WPS, kj = idx - ki * WPS;
    float w = 0.f;
    if (kj < KS) w = crow[qidx(ki - RAD) * 13 + qidx(kj - RAD)] + kpe[ki * KS + kj];
    h2 v; v.x = (_Float16)w; v.y = (_Float16)w;
    w2[idx] = v;
  }
  __syncthreads();

  // ---- fill pair tile rows 25..88: xp[25+r][i] = (px_r[i], px_r[i+32]) ----
  // px_r[i] = x[r][i-25] for i-25 in [0,64), else 0
  const float* __restrict__ ximg = x + (size_t)img * (HW * HW);
  {
    const int r = tid >> 2, q = tid & 3;
    const int i0 = q * 21;
    const int iend = (i0 + 21 < 82) ? i0 + 21 : 82;
    h2* dst = &xp[(RAD + r) * XPS];
    const float* srow = ximg + r * HW;
    for (int i = i0; i < iend; ++i) {
      const float a = (i >= 25) ? srow[i - 25] : 0.f;   // col i-25 (<= 56 here)
      const float b = (i < 57) ? srow[i + 7] : 0.f;     // col i+32-25
      h2 v; v.x = (_Float16)a; v.y = (_Float16)b;
      dst[i] = v;
    }
  }
  __syncthreads();

  // ---- lane mapping: row_lo in octet (bank coverage); ki-split across wave pairs ----
  const int lane  = tid & 63, wv = tid >> 6;
  const int row   = (lane & 7) | (((lane >> 3) & 3) << 3) | ((wv & 1) << 5);  // 0..63
  const int strip = (lane >> 5) & 1;
  const int kih   = wv >> 1;            // 0: ki 0..25, 1: ki 26..50
  const int c0    = strip << 4;         // pair-col base 0 / 16

  float accf[32];
#pragma unroll
  for (int m = 0; m < 32; ++m) accf[m] = 0.f;

  const int kiend = kih ? KS : 26;
  int ki = kih ? 26 : 0;
#pragma unroll 1
  while (ki < kiend) {
    const int kstop = (ki + 8 < kiend) ? ki + 8 : kiend;
    h2 acc2[16];
    h2 zz; zz.x = (_Float16)0.f; zz.y = (_Float16)0.f;
#pragma unroll
    for (int j = 0; j < 16; ++j) acc2[j] = zz;

#pragma unroll 1
    for (; ki < kstop; ++ki) {
      const h2* xr = &xp[(row + ki) * XPS + c0];
      h2 P[68];
#pragma unroll
      for (int t = 0; t < 17; ++t)
        *(uint4*)&P[4 * t] = *(const uint4*)&xr[4 * t];     // ds_read_b128
      const h2* wr = &w2[ki * WPS];
#pragma unroll
      for (int kq = 0; kq < 13; ++kq) {
        h2 w4[4];
        *(uint4*)&w4[0] = *(const uint4*)&wr[4 * kq];       // uniform broadcast
#pragma unroll
        for (int t = 0; t < 4; ++t) {
#pragma unroll
          for (int j = 0; j < 16; ++j)
            acc2[j] = __builtin_elementwise_fma(P[j + 4 * kq + t], w4[t], acc2[j]);
        }
      }
    }
    // flush f16 pair-accumulators into f32 (every <=8 ki rows)
#pragma unroll
    for (int j = 0; j < 16; ++j) {
      accf[2 * j]     += (float)acc2[j].x;
      accf[2 * j + 1] += (float)acc2[j].y;
    }
  }

  // ---- combine ki-halves via LDS stage (reuse xp area), then write out ----
  __syncthreads();                       // all conv reads of xp/w2 done
  float* stage = (float*)xp;
  const int slot = ((row << 1) | strip) << 5;    // 32 f32 per (row,strip)
  if (kih) {
#pragma unroll
    for (int m = 0; m < 32; m += 4)
      *(float4*)&stage[slot + m] =
          make_float4(accf[m], accf[m + 1], accf[m + 2], accf[m + 3]);
  }
  __syncthreads();
  if (!kih) {
#pragma unroll
    for (int m = 0; m < 32; m += 4) {
      const float4 s = *(const float4*)&stage[slot + m];
      accf[m] += s.x; accf[m + 1] += s.y; accf[m + 2] += s.z; accf[m + 3] += s.w;
    }
    float* orow = out + (size_t)img * (HW * HW) + row * HW;
    // acc2[j] halves: even accf -> col c0+j, odd accf -> col c0+j+32
#pragma unroll
    for (int jq = 0; jq < 4; ++jq) {
      const int jb = 8 * jq;
      *(float4*)&orow[c0 + 4 * jq] =
          make_float4(accf[jb], accf[jb + 2], accf[jb + 4], accf[jb + 6]);
      *(float4*)&orow[c0 + 4 * jq + 32] =
          make_float4(accf[jb + 1], accf[jb + 3], accf[jb + 5], accf[jb + 7]);
    }
  }
}

extern "C" void kernel_launch(void* const* d_in, const int* in_sizes, int n_in,
                              void* d_out, int out_size, void* d_ws, size_t ws_size,
                              hipStream_t stream) {
  const float* x    = (const float*)d_in[0];
  const float* comp = (const float*)d_in[1];
  const float* kpe  = (const float*)d_in[2];
  float* out        = (float*)d_out;

  dwconv<<<dim3(16 * DIM), dim3(256), 0, stream>>>(x, comp, kpe, out);
}

// Round 7
// 179.647 us; speedup vs baseline: 2.3364x; 2.3364x over previous
//
#include <hip/hip_runtime.h>

#define KS 51
#define RAD 25
#define DIM 128
#define HW 64

typedef _Float16 f16x8 __attribute__((ext_vector_type(8)));
typedef float f32x4 __attribute__((ext_vector_type(4)));

// coords = [0,1,2,4,8,16,25]; quantise = largest coord <= |o|; signed index 0..12
__device__ __forceinline__ int qidx(int o) {
  int a = o < 0 ? -o : o;
  int r;
  if (a >= 25)      r = 6;
  else if (a >= 16) r = 5;
  else if (a >= 8)  r = 4;
  else if (a >= 4)  r = 3;
  else if (a >= 2)  r = 2;
  else              r = a;
  return o < 0 ? 6 - r : 6 + r;
}

// Block: 256 threads = 4 waves = 2 images (same channel c, batches 2bp,2bp+1)
//        x 2 column-half waves. Grid 1024 = 8 bp x 128 ch.
// Stage-1 MFMA: per input row s, D[ki][c] = sum_kj W[ki][kj] * xpad_s[c+kj].
// Skew folded via rotated weight rows: slot p holds out-row r = (-p) mod 64,
// reads W-row rho=(s+25+p)&63 (rows 51..63 zero). Zero at birth, flush at done.
__launch_bounds__(256, 2)
__global__ void dwconv_mfma(const float* __restrict__ x,
                            const float* __restrict__ comp,
                            const float* __restrict__ kpe,
                            float* __restrict__ out) {
  __shared__ unsigned short xs[2 * 64 * 256];  // [img][row][copy0 128 | copy1 128] f16
  __shared__ unsigned short wl[64 * 72];       // [ki][kj0..71]; ki>=51 or kj>=51 -> 0

  const int tid = threadIdx.x;
  const int bid = blockIdx.x;
  const int ch  = bid & 127;
  const int bp  = bid >> 7;

  // ---- zero x tile (pads + copy tails) ----
  {
    uint4 z; z.x = z.y = z.z = z.w = 0u;
    uint4* p = (uint4*)xs;
    for (int i = tid; i < (2 * 64 * 256) / 8; i += 256) p[i] = z;
  }
  __syncthreads();

  // ---- weights: dense 51x51 = gather(comp) + kpe, f16, zero-padded to 64x72 ----
  {
    const float* crow = comp + ch * 169;
    for (int t = tid; t < 64 * 72; t += 256) {
      const int ki = t / 72, kj = t - ki * 72;
      float w = 0.f;
      if (ki < KS && kj < KS)
        w = crow[qidx(ki - RAD) * 13 + qidx(kj - RAD)] + kpe[ki * KS + kj];
      wl[t] = __builtin_bit_cast(unsigned short, (_Float16)w);
    }
  }

  // ---- x rows -> f16, two 1-element-shifted copies (even-aligned window reads) ----
  {
    const int ii = tid >> 7, rr = (tid >> 1) & 63, hh = tid & 1;
    const float* src = x + ((size_t)((bp * 2 + ii) * DIM + ch)) * (HW * HW) + rr * HW + hh * 32;
    unsigned short* row = &xs[ii * 16384 + rr * 256];
#pragma unroll
    for (int j = 0; j < 32; ++j) {
      const unsigned short u = __builtin_bit_cast(unsigned short, (_Float16)src[j]);
      const int e = RAD + hh * 32 + j;   // xpad[e] = x[rr][e-25]
      row[e] = u;                        // copy0[e]   = xpad[e]
      row[128 + e - 1] = u;              // copy1[e-1] = xpad[e]
    }
  }
  __syncthreads();

  // ---- wave setup ----
  const int wv   = tid >> 6;
  const int lane = tid & 63;
  const int g    = lane >> 4;        // k-octet / D-row quad
  const int Lo   = lane & 15;        // A: m (c-offset); B/D: n (slot)
  const int wimg = wv >> 1;
  const int c0w  = (wv & 1) * 32;

  const int  pi    = Lo & 1;                         // parity copy select
  const bool m1    = (Lo & 2) != 0;                  // u&1, u = (Lo>>1)&3
  const bool m2    = (Lo & 4) != 0;                  // u&2
  const int  laneA = pi * 128 + 8 * (g + (Lo >> 3)); // aligned window base part
  const int  lo25  = Lo + RAD;

  f32x4 acc[2][4];
#pragma unroll
  for (int mt = 0; mt < 2; ++mt)
#pragma unroll
    for (int nt = 0; nt < 4; ++nt) acc[mt][nt] = (f32x4){0.f, 0.f, 0.f, 0.f};

  const unsigned short* xrow = &xs[wimg * 16384];
  float* outimg = out + ((size_t)((bp * 2 + wimg) * DIM + ch)) * (HW * HW);

#pragma unroll 1
  for (int s = 0; s < 64; ++s, xrow += 256) {
    // birth-zero: slot pb = 39-s (row r = s+25) — kill pre-birth wrap garbage
    if (s >= 1 && s <= 38) {
      const int pb = 39 - s;
      const bool zl = (Lo == (pb & 15));
      const int ntb = pb >> 4;
#pragma unroll
      for (int nt = 0; nt < 4; ++nt)
        if (nt == ntb) {
#pragma unroll
          for (int mt = 0; mt < 2; ++mt)
#pragma unroll
            for (int q = 0; q < 4; ++q)
              acc[mt][nt][q] = zl ? 0.f : acc[mt][nt][q];
        }
    }

    const int lo25s = lo25 + s;

#pragma unroll
    for (int kjc = 0; kjc < 2; ++kjc) {
      // B: rotated weight rows, 8 consecutive kj per lane (b128, aligned)
      f16x8 bf[4];
#pragma unroll
      for (int nt = 0; nt < 4; ++nt) {
        const int rho = (lo25s + 16 * nt) & 63;
        bf[nt] = __builtin_bit_cast(f16x8, *(const uint4*)&wl[rho * 72 + g * 8 + kjc * 32]);
      }
#pragma unroll
      for (int mt = 0; mt < 2; ++mt) {
        // A: Toeplitz window xpad_s[c0w+16mt+32kjc + Lo+8g .. +7], parity-copy aligned
        const int eoff = laneA + c0w + 16 * mt + 32 * kjc;
        const uint4 da = *(const uint4*)&xrow[eoff];
        const uint4 db = *(const uint4*)&xrow[eoff + 8];
        const unsigned d0 = da.x, d1 = da.y, d2 = da.z, d3 = da.w;
        const unsigned d4 = db.x, d5 = db.y, d6 = db.z, d7 = db.w;
        const unsigned e0 = m2 ? d2 : d0, e1 = m2 ? d3 : d1, e2 = m2 ? d4 : d2,
                       e3 = m2 ? d5 : d3, e4 = m2 ? d6 : d4;
        uint4 sv;
        sv.x = m1 ? e1 : e0; sv.y = m1 ? e2 : e1; sv.z = m1 ? e3 : e2; sv.w = m1 ? e4 : e3;
        const f16x8 af = __builtin_bit_cast(f16x8, sv);
#pragma unroll
        for (int nt = 0; nt < 4; ++nt)
          acc[mt][nt] = __builtin_amdgcn_mfma_f32_16x16x32_f16(af, bf[nt], acc[mt][nt], 0, 0, 0);
      }
    }

    // flush completed row r = s-25 (slot pf), AFTER this step's MFMAs
    if (s >= 25) {
      const int pf = (89 - s) & 63;
      const int r  = s - 25;
      const bool fl = (Lo == (pf & 15));
      const int ntf = pf >> 4;
      float* orow = outimg + r * 64 + c0w + 4 * g;
#pragma unroll
      for (int nt = 0; nt < 4; ++nt)
        if (nt == ntf && fl) {
          *(float4*)&orow[0]  = make_float4(acc[0][nt][0], acc[0][nt][1], acc[0][nt][2], acc[0][nt][3]);
          *(float4*)&orow[16] = make_float4(acc[1][nt][0], acc[1][nt][1], acc[1][nt][2], acc[1][nt][3]);
        }
    }
  }

  // tail: rows 39..63 (slots p=1..25) — incomplete windows end at image bottom
#pragma unroll
  for (int p = 1; p <= 25; ++p) {
    const int nt = p >> 4;
    const int r  = 64 - p;
    if (Lo == (p & 15)) {
      float* orow = outimg + r * 64 + c0w + 4 * g;
      *(float4*)&orow[0]  = make_float4(acc[0][nt][0], acc[0][nt][1], acc[0][nt][2], acc[0][nt][3]);
      *(float4*)&orow[16] = make_float4(acc[1][nt][0], acc[1][nt][1], acc[1][nt][2], acc[1][nt][3]);
    }
  }
}

extern "C" void kernel_launch(void* const* d_in, const int* in_sizes, int n_in,
                              void* d_out, int out_size, void* d_ws, size_t ws_size,
                              hipStream_t stream) {
  const float* x    = (const float*)d_in[0];
  const float* comp = (const float*)d_in[1];
  const float* kpe  = (const float*)d_in[2];
  float* out        = (float*)d_out;

  dwconv_mfma<<<dim3(1024), dim3(256), 0, stream>>>(x, comp, kpe, out);
}

// Round 8
// 162.511 us; speedup vs baseline: 2.5828x; 1.1054x over previous
//
#include <hip/hip_runtime.h>

#define KS 51
#define RAD 25
#define DIM 128
#define HW 64
#define XSTR 136        // f16 per LDS row: 272 B = 17 x 16B (odd -> fill spreads banks)

typedef _Float16 f16x8 __attribute__((ext_vector_type(8)));
typedef float f32x4 __attribute__((ext_vector_type(4)));

// coords = [0,1,2,4,8,16,25]; quantise = largest coord <= |o|; signed index 0..12
__device__ __forceinline__ int qidx(int o) {
  int a = o < 0 ? -o : o;
  int r;
  if (a >= 25)      r = 6;
  else if (a >= 16) r = 5;
  else if (a >= 8)  r = 4;
  else if (a >= 4)  r = 3;
  else if (a >= 2)  r = 2;
  else              r = a;
  return o < 0 ? 6 - r : 6 + r;
}

__device__ __forceinline__ unsigned alignsel(unsigned hi, unsigned lo, unsigned sh) {
#if __has_builtin(__builtin_amdgcn_alignbit)
  return __builtin_amdgcn_alignbit(hi, lo, sh);
#else
  return (unsigned)((((unsigned long long)hi << 32) | (unsigned long long)lo) >> sh);
#endif
}

// Block: 256 threads = 4 waves, 4 images (same channel, batches 4*grp..4*grp+3).
// Wave w: c-half (w&1), image pair (w>>1). B (weight) fragments shared across the
// wave's 2 images -> 8 B-reads feed 32 MFMAs per step.
// Stage-1 MFMA per input row s: D[slot][c] += W[rho(s,slot)][kj] * xpad_s[c+kj],
// rho=(s+25+p)&63 (rows 51..63 zero); slot p owns out-row r=(-p)&63.
__launch_bounds__(256, 2)
__global__ void dwconv_mfma(const float* __restrict__ x,
                            const float* __restrict__ comp,
                            const float* __restrict__ kpe,
                            float* __restrict__ out) {
  __shared__ unsigned short xs[4 * 64 * XSTR];  // 69,632 B, single copy, halo 25
  __shared__ unsigned short wl[64 * 72];        // 9,216 B

  const int tid = threadIdx.x;
  const int bid = blockIdx.x;
  const int ch  = bid & 127;
  const int grp = bid >> 7;                     // 0..3

  // ---- zero x tile ----
  {
    uint4 z; z.x = z.y = z.z = z.w = 0u;
    uint4* p = (uint4*)xs;
    for (int i = tid; i < (4 * 64 * XSTR * 2) / 16; i += 256) p[i] = z;
  }
  // ---- weights: dense 51x51 = gather(comp) + kpe, f16, zero-padded to 64x72 ----
  {
    const float* crow = comp + ch * 169;
    for (int t = tid; t < 64 * 72; t += 256) {
      const int ki = t / 72, kj = t - ki * 72;
      float w = 0.f;
      if (ki < KS && kj < KS)
        w = crow[qidx(ki - RAD) * 13 + qidx(kj - RAD)] + kpe[ki * KS + kj];
      wl[t] = __builtin_bit_cast(unsigned short, (_Float16)w);
    }
  }
  __syncthreads();

  // ---- center fill: thread = one (img,row); reg-pack to f16 pairs, b32 stores ----
  {
    const int fimg = tid >> 6, frow = tid & 63;
    const float* src = x + ((size_t)((grp * 4 + fimg) * DIM + ch)) * (HW * HW) + frow * HW;
    float v[64];
#pragma unroll
    for (int j = 0; j < 16; ++j) *(float4*)&v[4 * j] = ((const float4*)src)[j];
    unsigned* dst32 = (unsigned*)&xs[fimg * (64 * XSTR) + frow * XSTR];
    // dword dw holds elements (2dw, 2dw+1); xpad[e] = x[e-25] for e in 25..88
#pragma unroll
    for (int k = 0; k < 33; ++k) {
      float lo, hi;
      if (k == 0)       { lo = 0.f;       hi = v[0]; }
      else if (k == 32) { lo = v[63];     hi = 0.f;  }
      else              { lo = v[2 * k - 1]; hi = v[2 * k]; }
      h2_pack: ;
      _Float16 plo = (_Float16)lo, phi = (_Float16)hi;
      unsigned u = (unsigned)__builtin_bit_cast(unsigned short, plo) |
                   ((unsigned)__builtin_bit_cast(unsigned short, phi) << 16);
      dst32[12 + k] = u;
    }
  }
  __syncthreads();

  // ---- wave setup ----
  const int wv   = tid >> 6;
  const int lane = tid & 63;
  const int g    = lane >> 4;          // A/B k-octet; D row-quad
  const int Lo   = lane & 15;          // A: m (c-offset); B/D: n (slot)
  const int c0w  = (wv & 1) * 32;
  const int ip   = (wv >> 1) * 2;      // first image of this wave's pair

  const bool m1 = (Lo & 2) != 0;       // dword-shift bit0
  const bool m2 = (Lo & 4) != 0;       // dword-shift bit1
  const unsigned sh16 = (unsigned)((Lo & 1) << 4);
  const int baseoff = 8 * (Lo >> 3) + 8 * g + c0w;   // + 16mt + 32kjc at use
  const int lo25 = Lo + RAD;

  f32x4 acc[2][2][4];                  // [img][mt][nt]
#pragma unroll
  for (int i = 0; i < 2; ++i)
#pragma unroll
    for (int mt = 0; mt < 2; ++mt)
#pragma unroll
      for (int nt = 0; nt < 4; ++nt) acc[i][mt][nt] = (f32x4){0.f, 0.f, 0.f, 0.f};

  const unsigned short* xb0 = &xs[(ip + 0) * (64 * XSTR)];
  const unsigned short* xb1 = &xs[(ip + 1) * (64 * XSTR)];
  float* oimg0 = out + ((size_t)((grp * 4 + ip + 0) * DIM + ch)) * (HW * HW);
  float* oimg1 = out + ((size_t)((grp * 4 + ip + 1) * DIM + ch)) * (HW * HW);

#pragma unroll 1
  for (int s = 0; s < 64; ++s) {
    // birth-zero slot pb = 39-s (out-row r = s+25) before this step's MFMAs
    if (s >= 1 && s <= 38) {
      const int pb = 39 - s;
      const bool zl = (Lo == (pb & 15));
      const int ntb = pb >> 4;
#pragma unroll
      for (int nt = 0; nt < 4; ++nt)
        if (nt == ntb) {
#pragma unroll
          for (int i = 0; i < 2; ++i)
#pragma unroll
            for (int mt = 0; mt < 2; ++mt)
#pragma unroll
              for (int q = 0; q < 4; ++q)
                acc[i][mt][nt][q] = zl ? 0.f : acc[i][mt][nt][q];
        }
    }

    // B fragments: 8 b128, shared by both images
    uint4 bf[4][2];
#pragma unroll
    for (int nt = 0; nt < 4; ++nt) {
      const int rho = (lo25 + s + 16 * nt) & 63;
      const int ro  = rho * 72 + g * 8;
      bf[nt][0] = *(const uint4*)&wl[ro];
      bf[nt][1] = *(const uint4*)&wl[ro + 32];
    }

#pragma unroll
    for (int i = 0; i < 2; ++i) {
      const unsigned short* xrow = (i == 0 ? xb0 : xb1) + s * XSTR;
#pragma unroll
      for (int mt = 0; mt < 2; ++mt) {
#pragma unroll
        for (int kjc = 0; kjc < 2; ++kjc) {
          const unsigned short* p = xrow + baseoff + 16 * mt + 32 * kjc;
          const uint4 da = *(const uint4*)p;        // same-row broadcast reads
          const uint4 db = *(const uint4*)(p + 8);
          const unsigned d0 = da.x, d1 = da.y, d2 = da.z, d3 = da.w;
          const unsigned d4 = db.x, d5 = db.y, d6 = db.z, d7 = db.w;
          const unsigned e0 = m1 ? d1 : d0, e1 = m1 ? d2 : d1, e2 = m1 ? d3 : d2,
                         e3 = m1 ? d4 : d3, e4 = m1 ? d5 : d4, e5 = m1 ? d6 : d5,
                         e6 = m1 ? d7 : d6;
          const unsigned f0 = m2 ? e2 : e0, f1 = m2 ? e3 : e1, f2 = m2 ? e4 : e2,
                         f3 = m2 ? e5 : e3, f4 = m2 ? e6 : e4;
          uint4 sv;
          sv.x = alignsel(f1, f0, sh16); sv.y = alignsel(f2, f1, sh16);
          sv.z = alignsel(f3, f2, sh16); sv.w = alignsel(f4, f3, sh16);
          const f16x8 af = __builtin_bit_cast(f16x8, sv);
#pragma unroll
          for (int nt = 0; nt < 4; ++nt)
            acc[i][mt][nt] = __builtin_amdgcn_mfma_f32_16x16x32_f16(
                af, __builtin_bit_cast(f16x8, bf[nt][kjc]), acc[i][mt][nt], 0, 0, 0);
        }
      }
    }

    // flush completed out-row r = s-25 (slot pf) after this step's MFMAs
    if (s >= 25) {
      const int pf = (89 - s) & 63;
      const int r  = s - 25;
      const bool fl = (Lo == (pf & 15));
      const int ntf = pf >> 4;
#pragma unroll
      for (int nt = 0; nt < 4; ++nt)
        if (nt == ntf && fl) {
          float* o0 = oimg0 + r * 64 + c0w + 4 * g;
          float* o1 = oimg1 + r * 64 + c0w + 4 * g;
          *(float4*)&o0[0]  = make_float4(acc[0][0][nt][0], acc[0][0][nt][1], acc[0][0][nt][2], acc[0][0][nt][3]);
          *(float4*)&o0[16] = make_float4(acc[0][1][nt][0], acc[0][1][nt][1], acc[0][1][nt][2], acc[0][1][nt][3]);
          *(float4*)&o1[0]  = make_float4(acc[1][0][nt][0], acc[1][0][nt][1], acc[1][0][nt][2], acc[1][0][nt][3]);
          *(float4*)&o1[16] = make_float4(acc[1][1][nt][0], acc[1][1][nt][1], acc[1][1][nt][2], acc[1][1][nt][3]);
        }
    }
  }

  // tail: out-rows 39..63 (slots p = 1..25)
#pragma unroll
  for (int p = 1; p <= 25; ++p) {
    const int nt = p >> 4;
    const int r  = 64 - p;
    if (Lo == (p & 15)) {
      float* o0 = oimg0 + r * 64 + c0w + 4 * g;
      float* o1 = oimg1 + r * 64 + c0w + 4 * g;
      *(float4*)&o0[0]  = make_float4(acc[0][0][nt][0], acc[0][0][nt][1], acc[0][0][nt][2], acc[0][0][nt][3]);
      *(float4*)&o0[16] = make_float4(acc[0][1][nt][0], acc[0][1][nt][1], acc[0][1][nt][2], acc[0][1][nt][3]);
      *(float4*)&o1[0]  = make_float4(acc[1][0][nt][0], acc[1][0][nt][1], acc[1][0][nt][2], acc[1][0][nt][3]);
      *(float4*)&o1[16] = make_float4(acc[1][1][nt][0], acc[1][1][nt][1], acc[1][1][nt][2], acc[1][1][nt][3]);
    }
  }
}

extern "C" void kernel_launch(void* const* d_in, const int* in_sizes, int n_in,
                              void* d_out, int out_size, void* d_ws, size_t ws_size,
                              hipStream_t stream) {
  const float* x    = (const float*)d_in[0];
  const float* comp = (const float*)d_in[1];
  const float* kpe  = (const float*)d_in[2];
  float* out        = (float*)d_out;

  dwconv_mfma<<<dim3(512), dim3(256), 0, stream>>>(x, comp, kpe, out);
}